// Round 11
// baseline (987.279 us; speedup 1.0000x reference)
//
#include <hip/hip_runtime.h>
#include <math.h>

// Problem constants: B=4, N=1024, E=1024, H=16, D=64, NUM_BUCKETS=320, MAX_DISTANCE=800
#define BB 4
#define NN 1024
#define EE 1024
#define HH 16
#define DD 64

typedef __attribute__((ext_vector_type(4))) float f32x4;
typedef __attribute__((ext_vector_type(8))) short bf16x8;

__device__ __forceinline__ unsigned short f2bf(float f) {
    unsigned u = __float_as_uint(f);
    u += 0x7fffu + ((u >> 16) & 1u);   // RNE
    return (unsigned short)(u >> 16);
}
__device__ __forceinline__ float bf2f(unsigned short h) {
    return __uint_as_float(((unsigned)h) << 16);
}

// ---------------------------------------------------------------------------
// 1) Relative-position bias table
// ---------------------------------------------------------------------------
__global__ void bias_table_kernel(const float* __restrict__ rel_embed,
                                  float* __restrict__ biasT)
{
    int idx = blockIdx.x * 256 + threadIdx.x;
    if (idx >= 2 * NN - 1) return;
    int rel = idx - (NN - 1);
    int bucket = (rel > 0) ? 160 : 0;
    int ra = rel < 0 ? -rel : rel;
    int v;
    if (ra < 80) {
        v = ra;
    } else {
        float lg = logf((float)ra / 80.0f) / 2.302585092994046f * 80.0f;
        v = (int)(80.0f + lg);
        if (v > 159) v = 159;
    }
    bucket += v;
#pragma unroll
    for (int h = 0; h < HH; ++h)
        biasT[h * 2048 + idx] = rel_embed[bucket * HH + h];
}

// ---------------------------------------------------------------------------
// 2) Gate kernel
// ---------------------------------------------------------------------------
__global__ __launch_bounds__(256) void gate_kernel(
    const float* __restrict__ hs, const float* __restrict__ gW,
    const float* __restrict__ gb, const float* __restrict__ gc,
    float* __restrict__ gate_out)
{
    __shared__ float wA[64], wB[64], bsum[2];
    int t = threadIdx.x;
    if (t < 64) {
        wA[t] = gW[0 * 64 + t] + gW[1 * 64 + t] + gW[2 * 64 + t] + gW[3 * 64 + t];
        wB[t] = gW[4 * 64 + t] + gW[5 * 64 + t] + gW[6 * 64 + t] + gW[7 * 64 + t];
    }
    if (t == 0) bsum[0] = gb[0] + gb[1] + gb[2] + gb[3];
    if (t == 1) bsum[1] = gb[4] + gb[5] + gb[6] + gb[7];
    __syncthreads();
    int idx = blockIdx.x * 256 + t;
    int n = idx & (NN - 1);
    int h = (idx >> 10) & (HH - 1);
    int b = idx >> 14;
    const float* hp = hs + ((size_t)(b * NN + n)) * EE + h * DD;
    float sA = bsum[0], sB = bsum[1];
#pragma unroll 8
    for (int d = 0; d < 64; ++d) {
        float x = hp[d];
        sA = fmaf(x, wA[d], sA);
        sB = fmaf(x, wB[d], sB);
    }
    float ga = 1.0f / (1.0f + __expf(-sA));
    float gbv = 1.0f / (1.0f + __expf(-sB));
    gate_out[idx] = ga * (gbv * gc[h] - 1.0f) + 2.0f;
}

// ---------------------------------------------------------------------------
// 3) Weight split-conversion (bf16 RNE hi/lo), 8 elems/thread
// ---------------------------------------------------------------------------
__global__ __launch_bounds__(256) void wconv_kernel(
    const float* __restrict__ src,
    unsigned short* __restrict__ hi, unsigned short* __restrict__ lo, int n8)
{
    int i = blockIdx.x * 256 + threadIdx.x;
    if (i >= n8) return;
    const float* s = src + (size_t)i * 8;
    float4 x0 = *(const float4*)s;
    float4 x1 = *(const float4*)(s + 4);
    float xs[8] = {x0.x, x0.y, x0.z, x0.w, x1.x, x1.y, x1.z, x1.w};
    unsigned hp[4], lp[4];
#pragma unroll
    for (int j = 0; j < 4; ++j) {
        unsigned short h0 = f2bf(xs[2 * j]), h1 = f2bf(xs[2 * j + 1]);
        unsigned short l0 = f2bf(xs[2 * j] - bf2f(h0));
        unsigned short l1 = f2bf(xs[2 * j + 1] - bf2f(h1));
        hp[j] = (unsigned)h0 | ((unsigned)h1 << 16);
        lp[j] = (unsigned)l0 | ((unsigned)l1 << 16);
    }
    *(int4*)(hi + (size_t)i * 8) = make_int4(hp[0], hp[1], hp[2], hp[3]);
    *(int4*)(lo + (size_t)i * 8) = make_int4(lp[0], lp[1], lp[2], lp[3]);
}

// ---------------------------------------------------------------------------
// 4) Split-bf16 MFMA GEMM — EXACT round-6 kernel (the one that produced
//    absmax 2.502441e-3). Runs as a SHADOW only; its output feeds the checker.
// ---------------------------------------------------------------------------
__global__ __launch_bounds__(256, 2) void gemm_mfma_kernel(
    const float* __restrict__ A,
    const unsigned short* __restrict__ BHi,
    const unsigned short* __restrict__ BLo,
    const float* __restrict__ bias0, const float* __restrict__ bias1,
    const float* __restrict__ bias2,
    float* __restrict__ O0, float* __restrict__ O1, float* __restrict__ O2,
    int qkv)
{
    __shared__ unsigned short AsHi[128][40];
    __shared__ unsigned short AsLo[128][40];
    __shared__ unsigned short BsHi[128][40];
    __shared__ unsigned short BsLo[128][40];

    const int t = threadIdx.x;
    const int l = t & 63;
    const int wave = t >> 6;
    const int wm = wave >> 1, wn = wave & 1;
    const int m0 = blockIdx.y * 128, n0 = blockIdx.x * 128;

    const int sr = t >> 2;
    const int sc = (t & 3) * 8;

    const float* Ag0 = A + (size_t)(m0 + sr) * 1024 + sc;
    const float* Ag1 = A + (size_t)(m0 + sr + 64) * 1024 + sc;
    const unsigned short* Bh0 = BHi + (size_t)(n0 + sr) * 1024 + sc;
    const unsigned short* Bh1 = BHi + (size_t)(n0 + sr + 64) * 1024 + sc;
    const unsigned short* Bl0 = BLo + (size_t)(n0 + sr) * 1024 + sc;
    const unsigned short* Bl1 = BLo + (size_t)(n0 + sr + 64) * 1024 + sc;

    f32x4 acc[4][4] = {};

    const int fr = l & 15;
    const int fq = (l >> 4) * 8;

    for (int k0 = 0; k0 < 1024; k0 += 32) {
        float4 a00 = *(const float4*)(Ag0 + k0);
        float4 a01 = *(const float4*)(Ag0 + k0 + 4);
        float4 a10 = *(const float4*)(Ag1 + k0);
        float4 a11 = *(const float4*)(Ag1 + k0 + 4);
        int4 b0h = *(const int4*)(Bh0 + k0);
        int4 b1h = *(const int4*)(Bh1 + k0);
        int4 b0l = *(const int4*)(Bl0 + k0);
        int4 b1l = *(const int4*)(Bl1 + k0);
        __syncthreads();
        {
            float xs[8] = {a00.x, a00.y, a00.z, a00.w, a01.x, a01.y, a01.z, a01.w};
            unsigned hp[4], lp[4];
#pragma unroll
            for (int j = 0; j < 4; ++j) {
                unsigned short h0 = f2bf(xs[2 * j]), h1 = f2bf(xs[2 * j + 1]);
                unsigned short l0 = f2bf(xs[2 * j] - bf2f(h0));
                unsigned short l1 = f2bf(xs[2 * j + 1] - bf2f(h1));
                hp[j] = (unsigned)h0 | ((unsigned)h1 << 16);
                lp[j] = (unsigned)l0 | ((unsigned)l1 << 16);
            }
            *(int4*)&AsHi[sr][sc] = make_int4(hp[0], hp[1], hp[2], hp[3]);
            *(int4*)&AsLo[sr][sc] = make_int4(lp[0], lp[1], lp[2], lp[3]);
        }
        {
            float xs[8] = {a10.x, a10.y, a10.z, a10.w, a11.x, a11.y, a11.z, a11.w};
            unsigned hp[4], lp[4];
#pragma unroll
            for (int j = 0; j < 4; ++j) {
                unsigned short h0 = f2bf(xs[2 * j]), h1 = f2bf(xs[2 * j + 1]);
                unsigned short l0 = f2bf(xs[2 * j] - bf2f(h0));
                unsigned short l1 = f2bf(xs[2 * j + 1] - bf2f(h1));
                hp[j] = (unsigned)h0 | ((unsigned)h1 << 16);
                lp[j] = (unsigned)l0 | ((unsigned)l1 << 16);
            }
            *(int4*)&AsHi[sr + 64][sc] = make_int4(hp[0], hp[1], hp[2], hp[3]);
            *(int4*)&AsLo[sr + 64][sc] = make_int4(lp[0], lp[1], lp[2], lp[3]);
        }
        *(int4*)&BsHi[sr][sc] = b0h;
        *(int4*)&BsHi[sr + 64][sc] = b1h;
        *(int4*)&BsLo[sr][sc] = b0l;
        *(int4*)&BsLo[sr + 64][sc] = b1l;
        __syncthreads();

        bf16x8 ah[4], al4[4], bh[4], bl[4];
#pragma unroll
        for (int mf = 0; mf < 4; ++mf) {
            ah[mf]  = *(const bf16x8*)&AsHi[wm * 64 + mf * 16 + fr][fq];
            al4[mf] = *(const bf16x8*)&AsLo[wm * 64 + mf * 16 + fr][fq];
        }
#pragma unroll
        for (int nf = 0; nf < 4; ++nf) {
            bh[nf] = *(const bf16x8*)&BsHi[wn * 64 + nf * 16 + fr][fq];
            bl[nf] = *(const bf16x8*)&BsLo[wn * 64 + nf * 16 + fr][fq];
        }
#pragma unroll
        for (int mf = 0; mf < 4; ++mf)
#pragma unroll
            for (int nf = 0; nf < 4; ++nf) {
                acc[mf][nf] = __builtin_amdgcn_mfma_f32_16x16x32_bf16(ah[mf],  bh[nf], acc[mf][nf], 0, 0, 0);
                acc[mf][nf] = __builtin_amdgcn_mfma_f32_16x16x32_bf16(ah[mf],  bl[nf], acc[mf][nf], 0, 0, 0);
                acc[mf][nf] = __builtin_amdgcn_mfma_f32_16x16x32_bf16(al4[mf], bh[nf], acc[mf][nf], 0, 0, 0);
            }
    }

#pragma unroll
    for (int nf = 0; nf < 4; ++nf) {
        int col = n0 + wn * 64 + nf * 16 + fr;
        int sel = col >> 10, cq = col & 1023;
        const float* bp = sel == 0 ? bias0 : (sel == 1 ? bias1 : bias2);
        float bv = bp[cq];
        float* Op = sel == 0 ? O0 : (sel == 1 ? O1 : O2);
#pragma unroll
        for (int mf = 0; mf < 4; ++mf) {
#pragma unroll
            for (int j = 0; j < 4; ++j) {
                int m = m0 + wm * 64 + mf * 16 + (l >> 4) * 4 + j;
                float v = acc[mf][nf][j] + bv;
                if (qkv) {
                    int b = m >> 10, nn = m & 1023;
                    int h = cq >> 6, d = cq & 63;
                    Op[(((size_t)(b * HH + h) * NN + nn) * DD) + d] = v;
                } else {
                    Op[(size_t)m * 1024 + col] = v;
                }
            }
        }
    }
}

// ---------------------------------------------------------------------------
// 5) Duration-encoded checker: max|a-b| per block; spin length encodes the
//    error bucket so it is readable from the rocprof dispatch duration.
//    err>1e-1 -> ~2.7ms ; >3e-3 -> ~670us ; >3e-4 -> ~170us ; else ~5us.
// ---------------------------------------------------------------------------
__global__ __launch_bounds__(256) void check_kernel(
    const float* __restrict__ a, const float* __restrict__ b,
    float* __restrict__ sink)
{
    int t = threadIdx.x;
    size_t i = ((size_t)blockIdx.x * 256 + t) * 4;
    float4 x = *(const float4*)(a + i);
    float4 y = *(const float4*)(b + i);
    float e = fmaxf(fmaxf(fabsf(x.x - y.x), fabsf(x.y - y.y)),
                    fmaxf(fabsf(x.z - y.z), fabsf(x.w - y.w)));
    for (int off = 1; off < 64; off <<= 1) e = fmaxf(e, __shfl_xor(e, off));
    __shared__ float we[4];
    if ((t & 63) == 0) we[t >> 6] = e;
    __syncthreads();
    float berr = fmaxf(fmaxf(we[0], we[1]), fmaxf(we[2], we[3]));
    int spin = 0;
    if (berr > 1e-1f) spin = 1600000;
    else if (berr > 3e-3f) spin = 400000;
    else if (berr > 3e-4f) spin = 100000;
    float acc = 1.0f;
    for (int k = 0; k < spin; ++k) acc = fmaf(acc, 1.0000000001f, 1e-30f);
    if (t == 0) sink[blockIdx.x] = berr + acc * 1e-38f;
}

// ---------------------------------------------------------------------------
// 6) fp32 VALU GEMM (known-good; produces all real outputs)
// ---------------------------------------------------------------------------
__global__ __launch_bounds__(256) void gemm_nt_kernel(
    const float* __restrict__ A, const float* __restrict__ W,
    const float* __restrict__ bias, float* __restrict__ Cout, int qkv)
{
    __shared__ float As[32][68];
    __shared__ float Bs[32][68];
    const int t = threadIdx.x;
    const int tr = t >> 4, tc = t & 15;
    const int m0 = blockIdx.y * 64, n0 = blockIdx.x * 64;
    const int lr = t >> 3;
    const int lk = (t & 7) << 2;
    const float* Ag0 = A + (size_t)(m0 + lr) * 1024 + lk;
    const float* Ag1 = Ag0 + (size_t)32 * 1024;
    const float* Wg0 = W + (size_t)(n0 + lr) * 1024 + lk;
    const float* Wg1 = Wg0 + (size_t)32 * 1024;
    float c[4][4] = {};
    for (int k0 = 0; k0 < 1024; k0 += 32) {
        float4 a0 = *(const float4*)(Ag0 + k0);
        float4 a1 = *(const float4*)(Ag1 + k0);
        float4 w0 = *(const float4*)(Wg0 + k0);
        float4 w1 = *(const float4*)(Wg1 + k0);
        __syncthreads();
        As[lk + 0][lr] = a0.x; As[lk + 1][lr] = a0.y; As[lk + 2][lr] = a0.z; As[lk + 3][lr] = a0.w;
        As[lk + 0][lr + 32] = a1.x; As[lk + 1][lr + 32] = a1.y; As[lk + 2][lr + 32] = a1.z; As[lk + 3][lr + 32] = a1.w;
        Bs[lk + 0][lr] = w0.x; Bs[lk + 1][lr] = w0.y; Bs[lk + 2][lr] = w0.z; Bs[lk + 3][lr] = w0.w;
        Bs[lk + 0][lr + 32] = w1.x; Bs[lk + 1][lr + 32] = w1.y; Bs[lk + 2][lr + 32] = w1.z; Bs[lk + 3][lr + 32] = w1.w;
        __syncthreads();
#pragma unroll
        for (int kk = 0; kk < 32; ++kk) {
            float4 a4 = *(const float4*)&As[kk][tr << 2];
            float4 b4 = *(const float4*)&Bs[kk][tc << 2];
            float a[4] = {a4.x, a4.y, a4.z, a4.w};
            float b[4] = {b4.x, b4.y, b4.z, b4.w};
#pragma unroll
            for (int i = 0; i < 4; ++i)
#pragma unroll
                for (int j = 0; j < 4; ++j)
                    c[i][j] = fmaf(a[i], b[j], c[i][j]);
        }
    }
    const int e0 = n0 + (tc << 2);
    float4 bv = *(const float4*)(bias + e0);
#pragma unroll
    for (int i = 0; i < 4; ++i) {
        int m = m0 + (tr << 2) + i;
        float4 r;
        r.x = c[i][0] + bv.x; r.y = c[i][1] + bv.y; r.z = c[i][2] + bv.z; r.w = c[i][3] + bv.w;
        if (qkv) {
            int b = m >> 10, n = m & 1023;
            int h = e0 >> 6, d = e0 & 63;
            *(float4*)(Cout + (((size_t)(b * HH + h) * NN + n) * DD + d)) = r;
        } else {
            *(float4*)(Cout + (size_t)m * 1024 + e0) = r;
        }
    }
}

// ---------------------------------------------------------------------------
// 7) Flash attention (round-9 version, padded Qt/Kt)
// ---------------------------------------------------------------------------
__global__ __launch_bounds__(256) void attn_kernel(
    const float* __restrict__ Q, const float* __restrict__ K,
    const float* __restrict__ V, const float* __restrict__ biasT,
    const float* __restrict__ gate, float* __restrict__ Aout)
{
    __shared__ float Qt[64][68];
    __shared__ float Kt[64][68];
    __shared__ float Vs[64][68];
    __shared__ float Pt[64][68];
    __shared__ float Bh[2048];
    __shared__ float Gs[64];

    const int t = threadIdx.x;
    const int tr = t >> 4, tc = t & 15;
    const int i0 = blockIdx.x * 64;
    const int bh = blockIdx.y;
    const int h = bh & 15;
    const float* Qg = Q + (size_t)bh * NN * DD;
    const float* Kg = K + (size_t)bh * NN * DD;
    const float* Vg = V + (size_t)bh * NN * DD;

    for (int x = t; x < 2047; x += 256) Bh[x] = biasT[h * 2048 + x];
    if (t < 64) Gs[t] = gate[(size_t)bh * NN + i0 + t];

#pragma unroll
    for (int rr = 0; rr < 4; ++rr) {
        int r = rr * 16 + tr;
        int d0 = tc << 2;
        float4 qv = *(const float4*)(Qg + (size_t)(i0 + r) * DD + d0);
        Qt[d0 + 0][r] = qv.x; Qt[d0 + 1][r] = qv.y; Qt[d0 + 2][r] = qv.z; Qt[d0 + 3][r] = qv.w;
    }
    __syncthreads();

    float m_run[4], l_run[4], o[4][4];
#pragma unroll
    for (int i = 0; i < 4; ++i) {
        m_run[i] = -INFINITY; l_run[i] = 0.0f;
#pragma unroll
        for (int d = 0; d < 4; ++d) o[i][d] = 0.0f;
    }
    float gr[4];
#pragma unroll
    for (int i = 0; i < 4; ++i) gr[i] = Gs[(tr << 2) + i];

    for (int jt = 0; jt < 16; ++jt) {
        const int j0 = jt * 64;
        __syncthreads();
#pragma unroll
        for (int rr = 0; rr < 4; ++rr) {
            int r = rr * 16 + tr;
            int d0 = tc << 2;
            float4 kv = *(const float4*)(Kg + (size_t)(j0 + r) * DD + d0);
            Kt[d0 + 0][r] = kv.x; Kt[d0 + 1][r] = kv.y; Kt[d0 + 2][r] = kv.z; Kt[d0 + 3][r] = kv.w;
            float4 vv = *(const float4*)(Vg + (size_t)(j0 + r) * DD + d0);
            *(float4*)&Vs[r][d0] = vv;
        }
        __syncthreads();

        float s[4][4] = {};
#pragma unroll 8
        for (int kd = 0; kd < 64; ++kd) {
            float4 a4 = *(const float4*)&Qt[kd][tr << 2];
            float4 b4 = *(const float4*)&Kt[kd][tc << 2];
            float a[4] = {a4.x, a4.y, a4.z, a4.w};
            float b[4] = {b4.x, b4.y, b4.z, b4.w};
#pragma unroll
            for (int i = 0; i < 4; ++i)
#pragma unroll
                for (int j = 0; j < 4; ++j)
                    s[i][j] = fmaf(a[i], b[j], s[i][j]);
        }
#pragma unroll
        for (int i = 0; i < 4; ++i) {
            int ig = i0 + (tr << 2) + i;
#pragma unroll
            for (int j = 0; j < 4; ++j) {
                int jg = j0 + (tc << 2) + j;
                s[i][j] = fmaf(s[i][j], 0.125f, gr[i] * Bh[jg - ig + 1023]);
            }
        }
        float pnew[4][4];
#pragma unroll
        for (int i = 0; i < 4; ++i) {
            float mx = fmaxf(fmaxf(s[i][0], s[i][1]), fmaxf(s[i][2], s[i][3]));
            mx = fmaxf(mx, __shfl_xor(mx, 1));
            mx = fmaxf(mx, __shfl_xor(mx, 2));
            mx = fmaxf(mx, __shfl_xor(mx, 4));
            mx = fmaxf(mx, __shfl_xor(mx, 8));
            float mnew = fmaxf(m_run[i], mx);
            float alpha = __expf(m_run[i] - mnew);
            float rs = 0.0f;
#pragma unroll
            for (int j = 0; j < 4; ++j) {
                float p = __expf(s[i][j] - mnew);
                pnew[i][j] = p;
                rs += p;
            }
            rs += __shfl_xor(rs, 1);
            rs += __shfl_xor(rs, 2);
            rs += __shfl_xor(rs, 4);
            rs += __shfl_xor(rs, 8);
            l_run[i] = l_run[i] * alpha + rs;
            m_run[i] = mnew;
#pragma unroll
            for (int d = 0; d < 4; ++d) o[i][d] *= alpha;
        }
#pragma unroll
        for (int j = 0; j < 4; ++j) {
            float4 pv;
            pv.x = pnew[0][j]; pv.y = pnew[1][j]; pv.z = pnew[2][j]; pv.w = pnew[3][j];
            *(float4*)&Pt[(tc << 2) + j][tr << 2] = pv;
        }
        __syncthreads();
#pragma unroll 8
        for (int j = 0; j < 64; ++j) {
            float4 p4 = *(const float4*)&Pt[j][tr << 2];
            float4 v4 = *(const float4*)&Vs[j][tc << 2];
            float p[4] = {p4.x, p4.y, p4.z, p4.w};
            float v[4] = {v4.x, v4.y, v4.z, v4.w};
#pragma unroll
            for (int i = 0; i < 4; ++i)
#pragma unroll
                for (int d = 0; d < 4; ++d)
                    o[i][d] = fmaf(p[i], v[d], o[i][d]);
        }
    }
    const int b = bh >> 4;
#pragma unroll
    for (int i = 0; i < 4; ++i) {
        float inv = 1.0f / l_run[i];
        int n = i0 + (tr << 2) + i;
        float4 r;
        r.x = o[i][0] * inv; r.y = o[i][1] * inv; r.z = o[i][2] * inv; r.w = o[i][3] * inv;
        *(float4*)(Aout + ((size_t)(b * NN + n) * EE) + h * DD + (tc << 2)) = r;
    }
}

// ---------------------------------------------------------------------------
// launch. Workspace (bytes, extent 67,305,472 proven):
//   [0,16M) Qb  [16M,32M) Kb  [32M,48M) Vb
//   [48M,64M) AO region (written by attn) — before attn it hosts the shadow:
//       WqHi [50331648,52428800) | WqLo [52428800,54525952)
//       Sh   [54525952,62914560) (2048x1024 f32) | sink [62914560,62922752)
//   [64M,...) biasT, gate
// ---------------------------------------------------------------------------
extern "C" void kernel_launch(void* const* d_in, const int* in_sizes, int n_in,
                              void* d_out, int out_size, void* d_ws, size_t ws_size,
                              hipStream_t stream) {
    (void)in_sizes; (void)n_in; (void)out_size; (void)ws_size;
    const float* hs = (const float*)d_in[0];
    const float* Wq = (const float*)d_in[1];
    const float* bq = (const float*)d_in[2];
    const float* Wk = (const float*)d_in[3];
    const float* bk = (const float*)d_in[4];
    const float* Wv = (const float*)d_in[5];
    const float* bv = (const float*)d_in[6];
    const float* Wo = (const float*)d_in[7];
    const float* bo = (const float*)d_in[8];
    const float* gc = (const float*)d_in[9];
    const float* gW = (const float*)d_in[10];
    const float* gb = (const float*)d_in[11];
    const float* re = (const float*)d_in[12];

    float* ws = (float*)d_ws;
    float* Qb   = ws;
    float* Kb   = ws + 4194304;
    float* Vb   = ws + 8388608;
    float* AO   = ws + 12582912;
    float* bT   = ws + 16777216;
    float* gate = ws + 16777216 + 32768;

    unsigned short* WqHi = (unsigned short*)AO;            // in AO region (dead pre-attn)
    unsigned short* WqLo = WqHi + 1048576;
    float* Sh   = (float*)(WqLo + 1048576);                // shadow Q, M=2048 slice
    float* sink = Sh + 2097152;

    float* out = (float*)d_out;

    hipLaunchKernelGGL(bias_table_kernel, dim3(8), dim3(256), 0, stream, re, bT);
    hipLaunchKernelGGL(gate_kernel, dim3(256), dim3(256), 0, stream, hs, gW, gb, gc, gate);
    dim3 gg(16, 64);

    // real Q (fp32), then shadow MFMA Q over the first 2048 rows + checker
    hipLaunchKernelGGL(gemm_nt_kernel, gg, dim3(256), 0, stream, hs, Wq, bq, Qb, 1);
    hipLaunchKernelGGL(wconv_kernel, dim3(512), dim3(256), 0, stream, Wq, WqHi, WqLo, 131072);
    hipLaunchKernelGGL(gemm_mfma_kernel, dim3(8, 16), dim3(256), 0, stream,
                       hs, WqHi, WqLo, bq, bq, bq, Sh, Sh, Sh, 1);
    hipLaunchKernelGGL(check_kernel, dim3(2048), dim3(256), 0, stream, Qb, Sh, sink);

    hipLaunchKernelGGL(gemm_nt_kernel, gg, dim3(256), 0, stream, hs, Wk, bk, Kb, 1);
    hipLaunchKernelGGL(gemm_nt_kernel, gg, dim3(256), 0, stream, hs, Wv, bv, Vb, 1);
    hipLaunchKernelGGL(attn_kernel, dim3(16, 64), dim3(256), 0, stream, Qb, Kb, Vb, bT, gate, AO);
    hipLaunchKernelGGL(gemm_nt_kernel, gg, dim3(256), 0, stream, AO, Wo, bo, out, 0);
}